// Round 12
// baseline (140.832 us; speedup 1.0000x reference)
//
#include <hip/hip_runtime.h>
#include <hip/hip_bf16.h>

typedef __attribute__((ext_vector_type(8))) short short8;
typedef __attribute__((ext_vector_type(4))) float f32x4;

#define NB 4096   // B
#define DD 256    // D
#define TWOB 8192
#define NMACRO 2080u   // symmetric 128x128 tiles: 64*65/2 (j >= i)
#define GSUM_BLOCKS 16
#define NPART 2096u    // gsum + macro blocks (8 x 262 exactly)

__device__ __forceinline__ unsigned short f2bf(float f) {
  unsigned int u = __float_as_uint(f);
  u += 0x7fffu + ((u >> 16) & 1u);
  return (unsigned short)(u >> 16);
}
__device__ __forceinline__ float bf2f(unsigned short s) {
  return __uint_as_float(((unsigned int)s) << 16);
}

// ws layout (bytes):
//   [0, 32768)          den[8192] f32 (zeroed by norm blocks 0..31)
//   [65536, 4259840)    znb 8192x256 bf16
//   [4259840, 4276224)  vsum_part[16][4][256] f32
//   [4276224, 4276480)  cnt_part[16][4] int
//   [4276480, 4280576)  ppos[1024] f32
//
// R29: register-direct fragments -- NO LDS staging, NO barriers in the
// macro loop. Nine structural variants (R18-R28) left den at 44+-2us;
// R26 (half the barriers) being NEUTRAL killed the per-interval model:
// the invariant cost is the whole global_load_lds+vmcnt+convoy
// choreography. Fragment layout decoded from the proven swizzle chain:
// lane l holds row=base+(l&15), k=kt*32+(l>>4)*8 for BOTH A and B ->
// plain per-lane 16B global loads reproduce it exactly (lanes r,r+16,
// r+32,r+48 form one contiguous 64B line per row). znb (4MB) is
// L2-resident per XCD; redundant per-wave panel reads (~532MB L2) cost
// ~14us at the 36.9TB/s L2 ceiling. Each wave free-runs load->MFMA with
// 1-step named-reg prefetch (~164 VGPR -> ~12 waves/CU; LDS 16.5KB
// epilogue/gsum scratch only). 128x128 symmetric tiles (2080, j>=i),
// 4 waves x 64x64; 2096=8x262 bijective XCD swizzle; R22 norm/tail.

// ---------------- kernel A: zero den; normalize -> znb bf16; ppos ---------
__global__ __launch_bounds__(256) void norm_kernel(const float* __restrict__ zi,
                                                   const float* __restrict__ zj,
                                                   float* __restrict__ wsf,
                                                   float* __restrict__ ppos,
                                                   unsigned short* __restrict__ znb) {
  __shared__ float sred[4];
  if (blockIdx.x < 32) wsf[blockIdx.x * 256 + threadIdx.x] = 0.f;
  const int lane = threadIdx.x & 63, wave = threadIdx.x >> 6;
  const int i = blockIdx.x * 4 + wave;

  float4 a = ((const float4*)(zi + (size_t)i * DD))[lane];
  float4 b = ((const float4*)(zj + (size_t)i * DD))[lane];
  float sa = a.x * a.x + a.y * a.y + a.z * a.z + a.w * a.w;
  float sb = b.x * b.x + b.y * b.y + b.z * b.z + b.w * b.w;
  float sab = a.x * b.x + a.y * b.y + a.z * b.z + a.w * b.w;
#pragma unroll
  for (int m = 32; m >= 1; m >>= 1) {
    sa += __shfl_xor(sa, m);
    sb += __shfl_xor(sb, m);
    sab += __shfl_xor(sab, m);
  }
  float ra = 1.0f / fmaxf(sqrtf(sa), 1e-8f);
  float rb = 1.0f / fmaxf(sqrtf(sb), 1e-8f);
  ushort4 oa, ob;
  oa.x = f2bf(a.x * ra); oa.y = f2bf(a.y * ra); oa.z = f2bf(a.z * ra); oa.w = f2bf(a.w * ra);
  ob.x = f2bf(b.x * rb); ob.y = f2bf(b.y * rb); ob.z = f2bf(b.z * rb); ob.w = f2bf(b.w * rb);
  ((ushort4*)(znb + (size_t)i * DD))[lane] = oa;
  ((ushort4*)(znb + (size_t)(i + NB) * DD))[lane] = ob;

  if (lane == 0) sred[wave] = sab * ra * rb;  // exact fp32 pos (row i)
  __syncthreads();
  if (threadIdx.x == 0)
    ppos[blockIdx.x] = sred[0] + sred[1] + sred[2] + sred[3];
}

// ---------------- kernel B: gsum + 128x128 tiles, register-direct ---------
__global__ __launch_bounds__(256, 2) void den_kernel(const int* __restrict__ sf,
                                                     float* __restrict__ wsf,
                                                     const unsigned short* __restrict__ znb,
                                                     float* __restrict__ vsum_part,
                                                     int* __restrict__ cnt_part) {
  __shared__ __align__(16) float Scr[4112];  // 16.4 KB: gsum reduce / epilogue

  float* den = wsf;

  const int tid = threadIdx.x;
  const int lane = tid & 63, wave = tid >> 6;  // wave 0..3
  const unsigned t_raw = blockIdx.y * 64u + blockIdx.x;
  if (t_raw >= NPART) return;  // spares
  // bijective XCD swizzle: 2096 = 8 x 262
  const unsigned t_lin = (t_raw & 7u) * 262u + (t_raw >> 3);

  if (t_lin < GSUM_BLOCKS) {
    // ---- gsum: 256 rows over 4 waves (64 rows each), LDS reduce ----------
    const int b = (int)t_lin;
    const int r0 = b * 256;
    float acc[4][4];
#pragma unroll
    for (int q = 0; q < 4; ++q)
#pragma unroll
      for (int e = 0; e < 4; ++e) acc[q][e] = 0.f;
    int cnt[4] = {0, 0, 0, 0};
    const int rw = r0 + wave * 64;
    for (int k = 0; k < 64; ++k) {
      int row = rw + k;
      int g = sf[row];
      ushort4 v = ((const ushort4*)(znb + (size_t)row * DD))[lane];
      float f0 = bf2f(v.x), f1 = bf2f(v.y), f2 = bf2f(v.z), f3 = bf2f(v.w);
#pragma unroll
      for (int q = 0; q < 4; ++q) {
        bool sel = (g == q);
        acc[q][0] += sel ? f0 : 0.f;
        acc[q][1] += sel ? f1 : 0.f;
        acc[q][2] += sel ? f2 : 0.f;
        acc[q][3] += sel ? f3 : 0.f;
        cnt[q] += sel ? 1 : 0;
      }
    }
    float4* lsd = (float4*)&Scr[0];   // 16 x 64 float4 = 16 KB
    int* lcnt = (int*)&Scr[4096];     // 16 ints
#pragma unroll
    for (int q = 0; q < 4; ++q) {
      float4 t;
      t.x = acc[q][0]; t.y = acc[q][1]; t.z = acc[q][2]; t.w = acc[q][3];
      lsd[(wave * 4 + q) * 64 + lane] = t;
    }
    if (lane == 0) {
#pragma unroll
      for (int q = 0; q < 4; ++q) lcnt[wave * 4 + q] = cnt[q];
    }
    __syncthreads();
    {
      int g = tid >> 6, l = tid & 63;
      float4 s0 = lsd[(0 + g) * 64 + l];
      float4 s1 = lsd[(4 + g) * 64 + l];
      float4 s2 = lsd[(8 + g) * 64 + l];
      float4 s3 = lsd[(12 + g) * 64 + l];
      float4 s;
      s.x = s0.x + s1.x + s2.x + s3.x;
      s.y = s0.y + s1.y + s2.y + s3.y;
      s.z = s0.z + s1.z + s2.z + s3.z;
      s.w = s0.w + s1.w + s2.w + s3.w;
      ((float4*)(vsum_part + (size_t)(b * 4 + g) * 256))[l] = s;
      if (tid < 4)
        cnt_part[b * 4 + tid] = lcnt[tid] + lcnt[4 + tid] + lcnt[8 + tid] + lcnt[12 + tid];
    }
    return;
  }

  // ---- one 128x128 symmetric tile (i,j), j >= i; 4 waves x (64x64) -------
  unsigned t = t_lin - GSUM_BLOCKS;
  unsigned i = 0;
  while (t >= 64u - i) { t -= 64u - i; ++i; }
  unsigned j = i + t;
  const size_t rowbase = (size_t)i * 128;
  const size_t colbase = (size_t)j * 128;
  const bool offdiag = (j > i);  // add col sums only for off-diagonal tiles

  const int wrow = wave & 1;   // 64-row half
  const int wcol = wave >> 1;  // 64-col half
  const int frow = lane & 15;        // fragment row (canonical layout)
  const int fk = (lane >> 4) * 8;    // fragment k-offset within 32-k step

  // per-fragment global base pointers (A and B have identical layout)
  const unsigned short* pA[4];
  const unsigned short* pB[4];
#pragma unroll
  for (int mi = 0; mi < 4; ++mi)
    pA[mi] = znb + (size_t)(rowbase + wrow * 64 + mi * 16 + frow) * DD + fk;
#pragma unroll
  for (int ni = 0; ni < 4; ++ni)
    pB[ni] = znb + (size_t)(colbase + wcol * 64 + ni * 16 + frow) * DD + fk;

  f32x4 zero = {0.f, 0.f, 0.f, 0.f};
  f32x4 acc[4][4];
#pragma unroll
  for (int a = 0; a < 4; ++a)
#pragma unroll
    for (int b2 = 0; b2 < 4; ++b2) acc[a][b2] = zero;

  // register-direct K-loop: no LDS, no barriers; 1-step named prefetch.
  short8 cA[4], cB[4], nA[4], nB[4];
#pragma unroll
  for (int mi = 0; mi < 4; ++mi) cA[mi] = *(const short8*)(pA[mi]);
#pragma unroll
  for (int ni = 0; ni < 4; ++ni) cB[ni] = *(const short8*)(pB[ni]);
#pragma unroll
  for (int kt = 0; kt < 8; ++kt) {
    if (kt < 7) {
#pragma unroll
      for (int mi = 0; mi < 4; ++mi) nA[mi] = *(const short8*)(pA[mi] + (kt + 1) * 32);
#pragma unroll
      for (int ni = 0; ni < 4; ++ni) nB[ni] = *(const short8*)(pB[ni] + (kt + 1) * 32);
    }
#pragma unroll
    for (int mi = 0; mi < 4; ++mi)
#pragma unroll
      for (int ni = 0; ni < 4; ++ni)
        acc[mi][ni] = __builtin_amdgcn_mfma_f32_16x16x32_bf16(cA[mi], cB[ni], acc[mi][ni], 0, 0, 0);
    if (kt < 7) {
#pragma unroll
      for (int mi = 0; mi < 4; ++mi) cA[mi] = nA[mi];
#pragma unroll
      for (int ni = 0; ni < 4; ++ni) cB[ni] = nB[ni];
    }
  }

  // epilogue: e = exp(2S); row/col sums; LDS combine; atomics.
  // C layout: col=lane&15, row=(lane>>4)*4+reg.
  float rsum[4][4];
  float csum[4];
#pragma unroll
  for (int mi = 0; mi < 4; ++mi)
#pragma unroll
    for (int r = 0; r < 4; ++r) rsum[mi][r] = 0.f;
#pragma unroll
  for (int ni = 0; ni < 4; ++ni) csum[ni] = 0.f;
#pragma unroll
  for (int mi = 0; mi < 4; ++mi)
#pragma unroll
    for (int ni = 0; ni < 4; ++ni)
#pragma unroll
      for (int r = 0; r < 4; ++r) {
        float e = __expf(2.0f * acc[mi][ni][r]);
        rsum[mi][r] += e;
        csum[ni] += e;
      }
#pragma unroll
  for (int m = 1; m < 16; m <<= 1)
#pragma unroll
    for (int mi = 0; mi < 4; ++mi)
#pragma unroll
      for (int r = 0; r < 4; ++r) rsum[mi][r] += __shfl_xor(rsum[mi][r], m);
#pragma unroll
  for (int m = 16; m < 64; m <<= 1)
#pragma unroll
    for (int ni = 0; ni < 4; ++ni) csum[ni] += __shfl_xor(csum[ni], m);

  float* Lr = &Scr[0];    // [2][128] indexed by wcol
  float* Lc = &Scr[256];  // [2][128] indexed by wrow
  if ((lane & 15) == 0) {
    int h = lane >> 4;
#pragma unroll
    for (int mi = 0; mi < 4; ++mi)
#pragma unroll
      for (int r = 0; r < 4; ++r)
        Lr[wcol * 128 + wrow * 64 + mi * 16 + h * 4 + r] = rsum[mi][r];
  }
  if (lane < 16) {
#pragma unroll
    for (int ni = 0; ni < 4; ++ni)
      Lc[wrow * 128 + wcol * 64 + ni * 16 + lane] = csum[ni];
  }
  __syncthreads();
  if (tid < 128) {
    unsafeAtomicAdd(&den[rowbase + tid], Lr[tid] + Lr[128 + tid]);
  } else if (offdiag) {
    int cc = tid - 128;
    unsafeAtomicAdd(&den[colbase + cc], Lc[cc] + Lc[128 + cc]);
  }
}

// ---------------- kernel C: tail (1 block x 1024) -------------------------
__global__ __launch_bounds__(1024) void tail_kernel(const float* __restrict__ wsf,
                                                    const float* __restrict__ vsum_part,
                                                    const int* __restrict__ cnt_part,
                                                    const float* __restrict__ ppos,
                                                    float* __restrict__ out) {
  __shared__ float sred[48];
  const float* den = wsf;
  const int tid = threadIdx.x;
  const int lane = tid & 63, wave = tid >> 6;  // 16 waves

  const float e2 = __expf(2.0f);
  float ls = 0.f;
#pragma unroll
  for (int k = 0; k < 8; ++k) ls += __logf(den[k * 1024 + tid] - e2);
#pragma unroll
  for (int m = 32; m >= 1; m >>= 1) ls += __shfl_xor(ls, m);
  if (lane == 0) sred[wave] = ls;

  float pp = ppos[tid];
#pragma unroll
  for (int m = 32; m >= 1; m >>= 1) pp += __shfl_xor(pp, m);
  if (lane == 0) sred[16 + wave] = pp;

  // group col-sums: thread t -> g = t>>8, col = t&255 (g wave-uniform)
  {
    int g = tid >> 8, col = tid & 255;
    float v = 0.f;
#pragma unroll
    for (int b = 0; b < 16; ++b) v += vsum_part[(size_t)(b * 4 + g) * 256 + col];
    float gp = v * v;
#pragma unroll
    for (int m = 32; m >= 1; m >>= 1) gp += __shfl_xor(gp, m);
    if (lane == 0) sred[32 + wave] = gp;  // wave w -> group w>>2
  }
  __syncthreads();
  if (tid == 0) {
    float lsum = 0.f, psum = 0.f;
#pragma unroll
    for (int w = 0; w < 16; ++w) { lsum += sred[w]; psum += sred[16 + w]; }
    float contrastive = (lsum - 4.0f * psum) / (float)TWOB;
    float fsum = 0.f;
    int uniq = 0;
#pragma unroll
    for (int q = 0; q < 4; ++q) {
      int ci = 0;
#pragma unroll
      for (int b = 0; b < 16; ++b) ci += cnt_part[b * 4 + q];
      float gsq = sred[32 + q * 4] + sred[33 + q * 4] + sred[34 + q * 4] + sred[35 + q * 4];
      float cf = (float)ci;
      if (ci > 0) uniq++;
      if (ci > 1) fsum += gsq / (cf * (cf - 1.0f));
    }
    out[0] = contrastive + 0.1f * (fsum / (uniq > 0 ? (float)uniq : 1.0f));
  }
}

extern "C" void kernel_launch(void* const* d_in, const int* in_sizes, int n_in,
                              void* d_out, int out_size, void* d_ws, size_t ws_size,
                              hipStream_t stream) {
  const float* zi = (const float*)d_in[0];
  const float* zj = (const float*)d_in[1];
  const int* sf = (const int*)d_in[2];
  float* out = (float*)d_out;
  char* ws = (char*)d_ws;
  float* wsf = (float*)ws;                              // den
  unsigned short* znb = (unsigned short*)(ws + 65536);  // 8192x256 bf16 (4MB)
  float* vsum_part = (float*)(ws + 4259840);            // 16x4x256 f32
  int* cnt_part = (int*)(ws + 4276224);                 // 16x4 int
  float* ppos = (float*)(ws + 4276480);                 // 1024 f32

  hipLaunchKernelGGL(norm_kernel, dim3(1024), dim3(256), 0, stream, zi, zj, wsf, ppos, znb);
  hipLaunchKernelGGL(den_kernel, dim3(64, 33), dim3(256), 0, stream,
                     sf, wsf, znb, vsum_part, cnt_part);
  hipLaunchKernelGGL(tail_kernel, dim3(1), dim3(1024), 0, stream,
                     wsf, vsum_part, cnt_part, ppos, out);
}

// Round 13
// 120.452 us; speedup vs baseline: 1.1692x; 1.1692x over previous
//
#include <hip/hip_runtime.h>
#include <hip/hip_bf16.h>

typedef __attribute__((ext_vector_type(8))) short short8;
typedef __attribute__((ext_vector_type(4))) float f32x4;
typedef __attribute__((address_space(1))) const void gvoid_t;
typedef __attribute__((address_space(3))) void lvoid_t;

#define NB 4096   // B
#define DD 256    // D
#define TWOB 8192
#define GSUM_BLOCKS 16
#define NPART 560u   // 16 gsum + 544 strip blocks (8 x 70 exactly)

__device__ __forceinline__ unsigned short f2bf(float f) {
  unsigned int u = __float_as_uint(f);
  u += 0x7fffu + ((u >> 16) & 1u);
  return (unsigned short)(u >> 16);
}
__device__ __forceinline__ float bf2f(unsigned short s) {
  return __uint_as_float(((unsigned int)s) << 16);
}

// ws layout (bytes):
//   [0, 32768)          den[8192] f32 (zeroed by norm blocks 0..31)
//   [65536, 4259840)    znb 8192x256 bf16
//   [4259840, 4276224)  vsum_part[16][4][256] f32
//   [4276224, 4276480)  cnt_part[16][4] int
//   [4276480, 4280576)  ppos[1024] f32
//
// R30: strip-mined A-reuse. R29 (register-direct, 532MB loads, den 77us)
// gave the first dose-response: den time tracks staged/loaded panel BYTES
// through a fixed-rate service path; barriers (R26), occupancy (R21/R28),
// tile order (R27) all null. This round cuts bytes while keeping the
// R22-proven skeleton: each block owns row-panel i and up to 4 col-tiles
// j (128x128). A (64KB, 8 slabs) staged ONCE into a dedicated LDS region
// inside tile 0's dist-2 counted pipeline; tiles 1..3 stream only B
// through 3 rotating 8KB buffers. Staged bytes 203->168MB (-17%), 560
// blocks (=8x70, bijective swizzle, no spares) -> 4x fewer prologues
// than R28. 8 waves x (64x32)/wave, acc=32 regs (no spill cliff), LDS
// 91KB, epilogue scratch separate (A stays resident; R24's liveness trap
// avoided: dynamic tile loop, no mega-unroll, no lambda epilogue).

// ---------------- kernel A: zero den; normalize -> znb bf16; ppos ---------
__global__ __launch_bounds__(256) void norm_kernel(const float* __restrict__ zi,
                                                   const float* __restrict__ zj,
                                                   float* __restrict__ wsf,
                                                   float* __restrict__ ppos,
                                                   unsigned short* __restrict__ znb) {
  __shared__ float sred[4];
  if (blockIdx.x < 32) wsf[blockIdx.x * 256 + threadIdx.x] = 0.f;
  const int lane = threadIdx.x & 63, wave = threadIdx.x >> 6;
  const int i = blockIdx.x * 4 + wave;

  float4 a = ((const float4*)(zi + (size_t)i * DD))[lane];
  float4 b = ((const float4*)(zj + (size_t)i * DD))[lane];
  float sa = a.x * a.x + a.y * a.y + a.z * a.z + a.w * a.w;
  float sb = b.x * b.x + b.y * b.y + b.z * b.z + b.w * b.w;
  float sab = a.x * b.x + a.y * b.y + a.z * b.z + a.w * b.w;
#pragma unroll
  for (int m = 32; m >= 1; m >>= 1) {
    sa += __shfl_xor(sa, m);
    sb += __shfl_xor(sb, m);
    sab += __shfl_xor(sab, m);
  }
  float ra = 1.0f / fmaxf(sqrtf(sa), 1e-8f);
  float rb = 1.0f / fmaxf(sqrtf(sb), 1e-8f);
  ushort4 oa, ob;
  oa.x = f2bf(a.x * ra); oa.y = f2bf(a.y * ra); oa.z = f2bf(a.z * ra); oa.w = f2bf(a.w * ra);
  ob.x = f2bf(b.x * rb); ob.y = f2bf(b.y * rb); ob.z = f2bf(b.z * rb); ob.w = f2bf(b.w * rb);
  ((ushort4*)(znb + (size_t)i * DD))[lane] = oa;
  ((ushort4*)(znb + (size_t)(i + NB) * DD))[lane] = ob;

  if (lane == 0) sred[wave] = sab * ra * rb;  // exact fp32 pos (row i)
  __syncthreads();
  if (threadIdx.x == 0)
    ppos[blockIdx.x] = sred[0] + sred[1] + sred[2] + sred[3];
}

// ---------------- kernel B: gsum + strip-mined 128x128 tiles --------------
__global__ __launch_bounds__(512, 2) void den_kernel(const int* __restrict__ sf,
                                                     float* __restrict__ wsf,
                                                     const unsigned short* __restrict__ znb,
                                                     float* __restrict__ vsum_part,
                                                     int* __restrict__ cnt_part) {
  __shared__ __align__(16) unsigned short As8[8][4096];  // 64 KB: full A panel, 8 slabs
  __shared__ __align__(16) unsigned short Bs[3][4096];   // 24 KB: B slabs, 3 rotating
  __shared__ __align__(16) float Scr[768];               // 3 KB: epilogue / gsum cnt

  float* den = wsf;

  const int tid = threadIdx.x;
  const int lane = tid & 63, wave = tid >> 6;  // wave 0..7
  const unsigned t_raw = blockIdx.y * 70u + blockIdx.x;
  // bijective XCD swizzle: 560 = 8 x 70, no spares
  const unsigned t_lin = (t_raw & 7u) * 70u + (t_raw >> 3);

  if (t_lin < GSUM_BLOCKS) {
    // ---- gsum: 256 rows over 8 waves (32 rows each), LDS reduce ----------
    const int b = (int)t_lin;
    const int r0 = b * 256;
    float acc[4][4];
#pragma unroll
    for (int q = 0; q < 4; ++q)
#pragma unroll
      for (int e = 0; e < 4; ++e) acc[q][e] = 0.f;
    int cnt[4] = {0, 0, 0, 0};
    const int rw = r0 + wave * 32;
    for (int k = 0; k < 32; ++k) {
      int row = rw + k;
      int g = sf[row];
      ushort4 v = ((const ushort4*)(znb + (size_t)row * DD))[lane];
      float f0 = bf2f(v.x), f1 = bf2f(v.y), f2 = bf2f(v.z), f3 = bf2f(v.w);
#pragma unroll
      for (int q = 0; q < 4; ++q) {
        bool sel = (g == q);
        acc[q][0] += sel ? f0 : 0.f;
        acc[q][1] += sel ? f1 : 0.f;
        acc[q][2] += sel ? f2 : 0.f;
        acc[q][3] += sel ? f3 : 0.f;
        cnt[q] += sel ? 1 : 0;
      }
    }
    float4* lsd = (float4*)&As8[0][0];  // 32 x 64 float4 = 32 KB
    int* lcnt = (int*)&Scr[0];          // 32 ints
#pragma unroll
    for (int q = 0; q < 4; ++q) {
      float4 t;
      t.x = acc[q][0]; t.y = acc[q][1]; t.z = acc[q][2]; t.w = acc[q][3];
      lsd[(wave * 4 + q) * 64 + lane] = t;
    }
    if (lane == 0) {
#pragma unroll
      for (int q = 0; q < 4; ++q) lcnt[wave * 4 + q] = cnt[q];
    }
    __syncthreads();
    if (tid < 256) {
      int g = tid >> 6, l = tid & 63;
      float4 s = {0.f, 0.f, 0.f, 0.f};
#pragma unroll
      for (int w = 0; w < 8; ++w) {
        float4 sv = lsd[(w * 4 + g) * 64 + l];
        s.x += sv.x; s.y += sv.y; s.z += sv.z; s.w += sv.w;
      }
      ((float4*)(vsum_part + (size_t)(b * 4 + g) * 256))[l] = s;
      if (tid < 4) {
        int ci = 0;
#pragma unroll
        for (int w = 0; w < 8; ++w) ci += lcnt[w * 4 + tid];
        cnt_part[b * 4 + tid] = ci;
      }
    }
    return;
  }

  // ---- strip: row-panel i, col-tiles j0..j0+nt-1 (128x128 each) ----------
  unsigned t = t_lin - GSUM_BLOCKS;  // chunk id, 0..543
  unsigned i = 0;
  while (t >= ((67u - i) >> 2)) { t -= (67u - i) >> 2; ++i; }  // nch(i)=ceil((64-i)/4)
  const unsigned j0 = i + 4u * t;
  const int nt = (int)((64u - j0 < 4u) ? (64u - j0) : 4u);
  const size_t rowbase = (size_t)i * 128;

  const int u = lane >> 3;
  const int cp = (lane & 7) ^ u;
  const int ri = 2 * u + (cp >> 2);
  const int kelem = (cp & 3) * 8;
  const int slot = ((((lane & 1) << 2) | (lane >> 4)) ^ ((lane >> 1) & 7));
  const int fragoff = ((lane & 15) >> 1) * 128 + slot * 16;
  const int wrow = wave & 1;   // 64-row half
  const int wcol = wave >> 1;  // 32-col quarter (0..3)

  // A panel staging base (this wave stages 16 rows: wave*16..wave*16+15)
  const unsigned short* gA = znb + (rowbase + wave * 16 + ri) * DD + kelem;

  f32x4 zero = {0.f, 0.f, 0.f, 0.f};
  f32x4 acc[4][2];

  for (int tt = 0; tt < nt; ++tt) {
    const size_t colbase = (size_t)(j0 + tt) * 128;
    const bool offdiag = (j0 + tt) > i;
    const unsigned short* gB = znb + (colbase + wave * 16 + ri) * DD + kelem;

#pragma unroll
    for (int a = 0; a < 4; ++a)
#pragma unroll
      for (int b2 = 0; b2 < 2; ++b2) acc[a][b2] = zero;

    // prologue: stage slabs 0,1 (tile 0 also stages A slabs 0,1)
    if (tt == 0) {
      __builtin_amdgcn_global_load_lds((gvoid_t*)(gA + 0 * 32), (lvoid_t*)&As8[0][wave * 512], 16, 0, 0);
      __builtin_amdgcn_global_load_lds((gvoid_t*)(gB + 0 * 32), (lvoid_t*)&Bs[0][wave * 512], 16, 0, 0);
      __builtin_amdgcn_global_load_lds((gvoid_t*)(gA + 1 * 32), (lvoid_t*)&As8[1][wave * 512], 16, 0, 0);
      __builtin_amdgcn_global_load_lds((gvoid_t*)(gB + 1 * 32), (lvoid_t*)&Bs[1][wave * 512], 16, 0, 0);
    } else {
      __builtin_amdgcn_global_load_lds((gvoid_t*)(gB + 0 * 32), (lvoid_t*)&Bs[0][wave * 512], 16, 0, 0);
      __builtin_amdgcn_global_load_lds((gvoid_t*)(gB + 1 * 32), (lvoid_t*)&Bs[1][wave * 512], 16, 0, 0);
    }

#pragma unroll
    for (int kt = 0; kt < 8; ++kt) {
      if (kt < 7) asm volatile("s_waitcnt vmcnt(1)" ::: "memory");
      else        asm volatile("s_waitcnt vmcnt(0)" ::: "memory");
      __builtin_amdgcn_s_barrier();
      asm volatile("" ::: "memory");  // keep stage() below the barrier
      if (kt < 6) {
        if (tt == 0)
          __builtin_amdgcn_global_load_lds((gvoid_t*)(gA + (kt + 2) * 32),
                                           (lvoid_t*)&As8[kt + 2][wave * 512], 16, 0, 0);
        __builtin_amdgcn_global_load_lds((gvoid_t*)(gB + (kt + 2) * 32),
                                         (lvoid_t*)&Bs[(kt + 2) % 3][wave * 512], 16, 0, 0);
      }
      short8 af[4], bfr[2];
#pragma unroll
      for (int mi = 0; mi < 4; ++mi)
        af[mi] = *(const short8*)((const char*)&As8[0][0] + kt * 8192 + (wrow * 4 + mi) * 1024 + fragoff);
#pragma unroll
      for (int ni = 0; ni < 2; ++ni)
        bfr[ni] = *(const short8*)((const char*)&Bs[0][0] + (kt % 3) * 8192 + (wcol * 2 + ni) * 1024 + fragoff);
#pragma unroll
      for (int mi = 0; mi < 4; ++mi)
#pragma unroll
        for (int ni = 0; ni < 2; ++ni)
          acc[mi][ni] = __builtin_amdgcn_mfma_f32_16x16x32_bf16(af[mi], bfr[ni], acc[mi][ni], 0, 0, 0);
    }

    // epilogue: e = exp(2S); row/col sums; Scr combine; atomics.
    // C layout: col=lane&15, row=(lane>>4)*4+reg.
    {
      float rsum[4][4];
      float csum[2];
#pragma unroll
      for (int mi = 0; mi < 4; ++mi)
#pragma unroll
        for (int r = 0; r < 4; ++r) rsum[mi][r] = 0.f;
#pragma unroll
      for (int ni = 0; ni < 2; ++ni) csum[ni] = 0.f;
#pragma unroll
      for (int mi = 0; mi < 4; ++mi)
#pragma unroll
        for (int ni = 0; ni < 2; ++ni)
#pragma unroll
          for (int r = 0; r < 4; ++r) {
            float e = __expf(2.0f * acc[mi][ni][r]);
            rsum[mi][r] += e;
            csum[ni] += e;
          }
#pragma unroll
      for (int m = 1; m < 16; m <<= 1)
#pragma unroll
        for (int mi = 0; mi < 4; ++mi)
#pragma unroll
          for (int r = 0; r < 4; ++r) rsum[mi][r] += __shfl_xor(rsum[mi][r], m);
#pragma unroll
      for (int m = 16; m < 64; m <<= 1)
#pragma unroll
        for (int ni = 0; ni < 2; ++ni) csum[ni] += __shfl_xor(csum[ni], m);

      float* Lr = &Scr[0];    // [4][128] indexed by wcol
      float* Lc = &Scr[512];  // [2][128] indexed by wrow
      if ((lane & 15) == 0) {
        int h = lane >> 4;
#pragma unroll
        for (int mi = 0; mi < 4; ++mi)
#pragma unroll
          for (int r = 0; r < 4; ++r)
            Lr[wcol * 128 + wrow * 64 + mi * 16 + h * 4 + r] = rsum[mi][r];
      }
      if (lane < 16) {
#pragma unroll
        for (int ni = 0; ni < 2; ++ni)
          Lc[wrow * 128 + wcol * 32 + ni * 16 + lane] = csum[ni];
      }
      // LDS-only barrier (A stays resident; no vmcnt drain needed: queue
      // empty after kt=7's vmcnt(0))
      asm volatile("s_waitcnt lgkmcnt(0)" ::: "memory");
      __builtin_amdgcn_s_barrier();
      asm volatile("" ::: "memory");
      if (tid < 128) {
        unsafeAtomicAdd(&den[rowbase + tid],
                        Lr[tid] + Lr[128 + tid] + Lr[256 + tid] + Lr[384 + tid]);
      } else if (offdiag && tid < 256) {
        int cc = tid - 128;
        unsafeAtomicAdd(&den[colbase + cc], Lc[cc] + Lc[128 + cc]);
      }
    }
  }
}

// ---------------- kernel C: tail (1 block x 1024) -------------------------
__global__ __launch_bounds__(1024) void tail_kernel(const float* __restrict__ wsf,
                                                    const float* __restrict__ vsum_part,
                                                    const int* __restrict__ cnt_part,
                                                    const float* __restrict__ ppos,
                                                    float* __restrict__ out) {
  __shared__ float sred[48];
  const float* den = wsf;
  const int tid = threadIdx.x;
  const int lane = tid & 63, wave = tid >> 6;  // 16 waves

  const float e2 = __expf(2.0f);
  float ls = 0.f;
#pragma unroll
  for (int k = 0; k < 8; ++k) ls += __logf(den[k * 1024 + tid] - e2);
#pragma unroll
  for (int m = 32; m >= 1; m >>= 1) ls += __shfl_xor(ls, m);
  if (lane == 0) sred[wave] = ls;

  float pp = ppos[tid];
#pragma unroll
  for (int m = 32; m >= 1; m >>= 1) pp += __shfl_xor(pp, m);
  if (lane == 0) sred[16 + wave] = pp;

  // group col-sums: thread t -> g = t>>8, col = t&255 (g wave-uniform)
  {
    int g = tid >> 8, col = tid & 255;
    float v = 0.f;
#pragma unroll
    for (int b = 0; b < 16; ++b) v += vsum_part[(size_t)(b * 4 + g) * 256 + col];
    float gp = v * v;
#pragma unroll
    for (int m = 32; m >= 1; m >>= 1) gp += __shfl_xor(gp, m);
    if (lane == 0) sred[32 + wave] = gp;  // wave w -> group w>>2
  }
  __syncthreads();
  if (tid == 0) {
    float lsum = 0.f, psum = 0.f;
#pragma unroll
    for (int w = 0; w < 16; ++w) { lsum += sred[w]; psum += sred[16 + w]; }
    float contrastive = (lsum - 4.0f * psum) / (float)TWOB;
    float fsum = 0.f;
    int uniq = 0;
#pragma unroll
    for (int q = 0; q < 4; ++q) {
      int ci = 0;
#pragma unroll
      for (int b = 0; b < 16; ++b) ci += cnt_part[b * 4 + q];
      float gsq = sred[32 + q * 4] + sred[33 + q * 4] + sred[34 + q * 4] + sred[35 + q * 4];
      float cf = (float)ci;
      if (ci > 0) uniq++;
      if (ci > 1) fsum += gsq / (cf * (cf - 1.0f));
    }
    out[0] = contrastive + 0.1f * (fsum / (uniq > 0 ? (float)uniq : 1.0f));
  }
}

extern "C" void kernel_launch(void* const* d_in, const int* in_sizes, int n_in,
                              void* d_out, int out_size, void* d_ws, size_t ws_size,
                              hipStream_t stream) {
  const float* zi = (const float*)d_in[0];
  const float* zj = (const float*)d_in[1];
  const int* sf = (const int*)d_in[2];
  float* out = (float*)d_out;
  char* ws = (char*)d_ws;
  float* wsf = (float*)ws;                              // den
  unsigned short* znb = (unsigned short*)(ws + 65536);  // 8192x256 bf16 (4MB)
  float* vsum_part = (float*)(ws + 4259840);            // 16x4x256 f32
  int* cnt_part = (int*)(ws + 4276224);                 // 16x4 int
  float* ppos = (float*)(ws + 4276480);                 // 1024 f32

  hipLaunchKernelGGL(norm_kernel, dim3(1024), dim3(256), 0, stream, zi, zj, wsf, ppos, znb);
  hipLaunchKernelGGL(den_kernel, dim3(70, 8), dim3(512), 0, stream,
                     sf, wsf, znb, vsum_part, cnt_part);
  hipLaunchKernelGGL(tail_kernel, dim3(1), dim3(1024), 0, stream,
                     wsf, vsum_part, cnt_part, ppos, out);
}